// Round 4
// baseline (778.580 us; speedup 1.0000x reference)
//
#include <hip/hip_runtime.h>

#define U_NUMC 100000
#define I_NUMC 50000
#define NNODES 150000
#define EMB 64
#define NBATCH 8192
#define NB_I ((I_NUMC + 255) / 256)   // 196 blocks over item histogram
#define BSH 4                          // 16 items per bucket
#define NBKT ((I_NUMC + 15) >> BSH)    // 3125 buckets
#define BCAP 2048                      // LDS staging capacity (edges)

// ---------------- zero small int buffer ----------------
__global__ __launch_bounds__(256) void k_zero(int* __restrict__ p, int n) {
    int i = blockIdx.x * blockDim.x + threadIdx.x;
    if (i < n) p[i] = 0;
}

// ---------------- user row_ptr via binary search (rows1 sorted) ----------------
__global__ __launch_bounds__(256) void k_uptr(const int* __restrict__ rows1, int E1,
                                              int* __restrict__ uptr) {
    int r = blockIdx.x * blockDim.x + threadIdx.x;
    if (r > U_NUMC) return;
    int lo = 0, hi = E1;                     // first e with rows1[e] >= r
    while (lo < hi) {
        int mid = (lo + hi) >> 1;
        if (rows1[mid] < r) lo = mid + 1; else hi = mid;
    }
    uptr[r] = lo;
}

// ---------------- histogram of items from first-half cols (= i + U_NUM) -------
__global__ __launch_bounds__(256) void k_hist(const int* __restrict__ cols1, int E1,
                                              int* __restrict__ hist) {
    int e = blockIdx.x * blockDim.x + threadIdx.x;
    if (e >= E1) return;
    atomicAdd(&hist[cols1[e] - U_NUMC], 1);
}

// ---------------- hierarchical scan: (1) per-block sums ----------------
__global__ __launch_bounds__(256) void k_scan1(const int* __restrict__ hist,
                                               int* __restrict__ bsum) {
    int b = blockIdx.x, t = threadIdx.x;
    int idx = b * 256 + t;
    int v = (idx < I_NUMC) ? hist[idx] : 0;
    #pragma unroll
    for (int o = 32; o; o >>= 1) v += __shfl_xor(v, o);
    __shared__ int ws4[4];
    if ((t & 63) == 0) ws4[t >> 6] = v;
    __syncthreads();
    if (t == 0) bsum[b] = ws4[0] + ws4[1] + ws4[2] + ws4[3];
}

// ---------------- (2) scan the 196 block sums (single block) ----------------
__global__ __launch_bounds__(256) void k_scan2(const int* __restrict__ bsum,
                                               int* __restrict__ boff,
                                               int* __restrict__ iptr) {
    __shared__ int lds[256];
    int t = threadIdx.x;
    int v = (t < NB_I) ? bsum[t] : 0;
    int x = v;
    #pragma unroll
    for (int o = 1; o < 256; o <<= 1) {
        lds[t] = x; __syncthreads();
        int y = (t >= o) ? lds[t - o] : 0; __syncthreads();
        x += y;
    }
    if (t < NB_I) boff[t] = x - v;           // exclusive block offset
    if (t == 255) iptr[I_NUMC] = x;          // grand total
}

// ------- (3) per-block rescan -> iptr; also bucket cursors at boundaries ------
__global__ __launch_bounds__(256) void k_scan3(const int* __restrict__ hist,
                                               const int* __restrict__ boff,
                                               int* __restrict__ iptr,
                                               int* __restrict__ bcur) {
    __shared__ int lds[256];
    int b = blockIdx.x, t = threadIdx.x;
    int idx = b * 256 + t;
    int v = (idx < I_NUMC) ? hist[idx] : 0;
    int x = v;
    #pragma unroll
    for (int o = 1; o < 256; o <<= 1) {
        lds[t] = x; __syncthreads();
        int y = (t >= o) ? lds[t - o] : 0; __syncthreads();
        x += y;
    }
    if (idx < I_NUMC) {
        int excl = boff[b] + x - v;
        iptr[idx] = excl;
        if ((idx & ((1 << BSH) - 1)) == 0) bcur[idx >> BSH] = excl;
    }
}

// ------- phase 1: scatter edges to coarse buckets (3125 append streams) -------
// payload.x = (i_low << 17) | u   (u < 2^17, i_low < 16)
__global__ __launch_bounds__(256) void k_scatter(const int* __restrict__ rows1,
                                                 const int* __restrict__ cols1,
                                                 const float* __restrict__ vals1,
                                                 int E1,
                                                 int* __restrict__ bcur,
                                                 int2* __restrict__ item_uv) {
    int e = blockIdx.x * blockDim.x + threadIdx.x;
    if (e >= E1) return;
    int i = cols1[e] - U_NUMC;
    int pos = atomicAdd(&bcur[i >> BSH], 1);
    item_uv[pos] = make_int2(((i & ((1 << BSH) - 1)) << 17) | rows1[e],
                             __float_as_int(vals1[e]));
}

// ------- phase 2: in-window counting sort -> exact item CSR, strip i_low ------
__global__ __launch_bounds__(256) void k_bsort(const int* __restrict__ iptr,
                                               int2* __restrict__ item_uv) {
    __shared__ int2 st[BCAP];
    __shared__ int lcur[1 << BSH];
    int b = blockIdx.x, t = threadIdx.x;
    int ibase = b << BSH;
    if (t < (1 << BSH)) {
        int item = ibase + t;
        lcur[t] = (item < I_NUMC) ? iptr[item] : 0;
    }
    int iend = ibase + (1 << BSH); if (iend > I_NUMC) iend = I_NUMC;
    int wbeg = iptr[ibase];
    int wend = iptr[iend];
    __syncthreads();
    for (int off = wbeg; off < wend; off += BCAP) {
        int n = min(BCAP, wend - off);
        for (int k = t; k < n; k += 256) st[k] = item_uv[off + k];
        __syncthreads();
        for (int k = t; k < n; k += 256) {
            int2 e = st[k];
            int pos = atomicAdd(&lcur[e.x >> 17], 1);
            item_uv[pos] = make_int2(e.x & 0x1FFFF, e.y);
        }
        __syncthreads();
    }
}

// ---------------- SpMM: one wave per output row, lane = dim -------------------
// 8-deep gather pipeline: all lanes hold a clamped edge (v=0 past end), so
// every group of 8 broadcast slots is valid; out-of-range slots gather the
// last row again (L2-hot) with weight 0.
// FIRST: gather from split uE/iE (base is wave-uniform: bipartite halves),
//        and initialize acc = own_feat + sum.
// LAST:  skip the fn store (only acc is consumed afterwards).
template <int FIRST, int LAST>
__global__ __launch_bounds__(256) void k_spmm(const float* __restrict__ uE,
                                              const float* __restrict__ iE,
                                              const float* __restrict__ f,
                                              float* __restrict__ fn,
                                              float* __restrict__ acc,
                                              const int* __restrict__ uptr,
                                              const int* __restrict__ cols1,
                                              const float* __restrict__ vals1,
                                              const int* __restrict__ iptr,
                                              const int2* __restrict__ item_uv) {
    int wave = (blockIdx.x * blockDim.x + threadIdx.x) >> 6;
    int lane = threadIdx.x & 63;
    if (wave >= NNODES) return;

    const bool isUser = (wave < U_NUMC);
    int beg, end;
    if (isUser) { beg = uptr[wave];           end = uptr[wave + 1]; }
    else        { int i = wave - U_NUMC; beg = iptr[i]; end = iptr[i + 1]; }

    // Gather base: user rows gather item nodes, item rows gather user nodes.
    const float* fb;
    if (FIRST) fb = isUser ? (iE - (size_t)U_NUMC * EMB) : uE;
    else       fb = f;

    float sum = 0.f;
    for (int base = beg; base < end; base += 64) {
        int idx = base + lane;
        int ld = min(idx, end - 1);
        int c; float v;
        if (isUser) {
            c = cols1[ld];
            v = (idx < end) ? vals1[ld] : 0.f;
        } else {
            int2 e = item_uv[ld];
            c = e.x;
            v = (idx < end) ? __int_as_float(e.y) : 0.f;
        }
        int n = min(64, end - base);
        for (int j = 0; j < n; j += 8) {
            float l[8], vv[8];
            #pragma unroll
            for (int t = 0; t < 8; ++t) {
                int cj = __shfl(c, j + t);
                vv[t] = __shfl(v, j + t);
                l[t] = fb[(size_t)cj * EMB + lane];   // 8 independent 256B gathers
            }
            #pragma unroll
            for (int t = 0; t < 8; ++t) sum += vv[t] * l[t];
        }
    }
    int o = wave * EMB + lane;
    if (!LAST) fn[o] = sum;
    if (FIRST) {
        float own = isUser ? uE[(size_t)wave * EMB + lane]
                           : iE[(size_t)(wave - U_NUMC) * EMB + lane];
        acc[o] = own + sum;
    } else {
        acc[o] += sum;
    }
}

// ---------------- batched dot of final embeddings ----------------
__global__ __launch_bounds__(256) void k_out(const float* __restrict__ acc,
                                             const int* __restrict__ userIdx,
                                             const int* __restrict__ itemIdx,
                                             float* __restrict__ out) {
    int wave = (blockIdx.x * blockDim.x + threadIdx.x) >> 6;
    int lane = threadIdx.x & 63;
    if (wave >= NBATCH) return;
    int u = userIdx[wave];
    int it = itemIdx[wave] + U_NUMC;
    float p = acc[u * EMB + lane] * acc[it * EMB + lane];
    #pragma unroll
    for (int offd = 32; offd; offd >>= 1) p += __shfl_xor(p, offd);
    if (lane == 0) out[wave] = p * (1.0f / 16.0f);   // (acc/4)·(acc/4)
}

extern "C" void kernel_launch(void* const* d_in, const int* in_sizes, int n_in,
                              void* d_out, int out_size, void* d_ws, size_t ws_size,
                              hipStream_t stream) {
    const float* uE      = (const float*)d_in[0];
    const float* iE      = (const float*)d_in[1];
    const int*   rows    = (const int*)d_in[2];    // [E], first half sorted by u
    const int*   cols    = (const int*)d_in[3];    // [E], first half = i + U_NUM
    const float* vals    = (const float*)d_in[4];  // [E], symmetric halves
    const int*   userIdx = (const int*)d_in[5];
    const int*   itemIdx = (const int*)d_in[6];
    const int E  = in_sizes[2];
    const int E1 = E / 2;

    char* ws = (char*)d_ws;
    size_t off = 0;
    auto alloc = [&](size_t bytes) -> void* {
        off = (off + 255) & ~(size_t)255;
        void* p = ws + off;
        off += bytes;
        return p;
    };
    float* f0      = (float*)alloc((size_t)NNODES * EMB * 4);
    float* f1      = (float*)alloc((size_t)NNODES * EMB * 4);
    float* acc     = (float*)alloc((size_t)NNODES * EMB * 4);
    int*   uptr    = (int*)alloc((size_t)(U_NUMC + 1) * 4);
    int*   iptr    = (int*)alloc((size_t)(I_NUMC + 1) * 4);
    int*   hist    = (int*)alloc((size_t)I_NUMC * 4);
    int*   bcur    = (int*)alloc((size_t)NBKT * 4);
    int*   bsum    = (int*)alloc((size_t)NB_I * 4);
    int*   boff    = (int*)alloc((size_t)NB_I * 4);
    int2*  item_uv = (int2*)alloc((size_t)E1 * 8);

    // zero histogram; build index structures (reused across all 3 layers)
    k_zero<<<(I_NUMC + 255) / 256, 256, 0, stream>>>(hist, I_NUMC);
    k_uptr<<<(U_NUMC + 256) / 256, 256, 0, stream>>>(rows, E1, uptr);
    k_hist<<<(E1 + 255) / 256, 256, 0, stream>>>(cols, E1, hist);
    k_scan1<<<NB_I, 256, 0, stream>>>(hist, bsum);
    k_scan2<<<1, 256, 0, stream>>>(bsum, boff, iptr);
    k_scan3<<<NB_I, 256, 0, stream>>>(hist, boff, iptr, bcur);
    k_scatter<<<(E1 + 255) / 256, 256, 0, stream>>>(rows, cols, vals, E1,
                                                    bcur, item_uv);
    k_bsort<<<NBKT, 256, 0, stream>>>(iptr, item_uv);

    // 3 propagation layers (layer 1 fused with init, layer 3 skips fn store)
    const int spmm_blocks = NNODES / 4;      // 4 waves (rows) per 256-thr block
    k_spmm<1, 0><<<spmm_blocks, 256, 0, stream>>>(uE, iE, nullptr, f1, acc,
                                                  uptr, cols, vals, iptr, item_uv);
    k_spmm<0, 0><<<spmm_blocks, 256, 0, stream>>>(uE, iE, f1, f0, acc,
                                                  uptr, cols, vals, iptr, item_uv);
    k_spmm<0, 1><<<spmm_blocks, 256, 0, stream>>>(uE, iE, f0, nullptr, acc,
                                                  uptr, cols, vals, iptr, item_uv);

    // final batched dot products
    k_out<<<NBATCH / 4, 256, 0, stream>>>(acc, userIdx, itemIdx, (float*)d_out);
}

// Round 8
// 677.389 us; speedup vs baseline: 1.1494x; 1.1494x over previous
//
#include <hip/hip_runtime.h>

#define U_NUMC 100000
#define I_NUMC 50000
#define NNODES 150000
#define EMB 64
#define NBATCH 8192
#define NB_I ((I_NUMC + 255) / 256)   // 196 blocks over item histogram

// ---------------- zero small int buffer ----------------
__global__ __launch_bounds__(256) void k_zero(int* __restrict__ p, int n) {
    int i = blockIdx.x * blockDim.x + threadIdx.x;
    if (i < n) p[i] = 0;
}

// ---------------- user row_ptr via binary search (rows1 sorted) ----------------
__global__ __launch_bounds__(256) void k_uptr(const int* __restrict__ rows1, int E1,
                                              int* __restrict__ uptr) {
    int r = blockIdx.x * blockDim.x + threadIdx.x;
    if (r > U_NUMC) return;
    int lo = 0, hi = E1;                     // first e with rows1[e] >= r
    while (lo < hi) {
        int mid = (lo + hi) >> 1;
        if (rows1[mid] < r) lo = mid + 1; else hi = mid;
    }
    uptr[r] = lo;
}

// ---------------- histogram of items from first-half cols (= i + U_NUM) -------
__global__ __launch_bounds__(256) void k_hist(const int* __restrict__ cols1, int E1,
                                              int* __restrict__ hist) {
    int e = blockIdx.x * blockDim.x + threadIdx.x;
    if (e >= E1) return;
    atomicAdd(&hist[cols1[e] - U_NUMC], 1);
}

// ---------------- hierarchical scan: (1) per-block sums ----------------
__global__ __launch_bounds__(256) void k_scan1(const int* __restrict__ hist,
                                               int* __restrict__ bsum) {
    int b = blockIdx.x, t = threadIdx.x;
    int idx = b * 256 + t;
    int v = (idx < I_NUMC) ? hist[idx] : 0;
    #pragma unroll
    for (int o = 32; o; o >>= 1) v += __shfl_xor(v, o);
    __shared__ int ws4[4];
    if ((t & 63) == 0) ws4[t >> 6] = v;
    __syncthreads();
    if (t == 0) bsum[b] = ws4[0] + ws4[1] + ws4[2] + ws4[3];
}

// ---------------- (2) scan the 196 block sums (single block) ----------------
__global__ __launch_bounds__(256) void k_scan2(const int* __restrict__ bsum,
                                               int* __restrict__ boff,
                                               int* __restrict__ iptr) {
    __shared__ int lds[256];
    int t = threadIdx.x;
    int v = (t < NB_I) ? bsum[t] : 0;
    int x = v;
    #pragma unroll
    for (int o = 1; o < 256; o <<= 1) {
        lds[t] = x; __syncthreads();
        int y = (t >= o) ? lds[t - o] : 0; __syncthreads();
        x += y;
    }
    if (t < NB_I) boff[t] = x - v;           // exclusive block offset
    if (t == 255) iptr[I_NUMC] = x;          // grand total
}

// ---------------- (3) per-block rescan + write iptr & cursor ----------------
__global__ __launch_bounds__(256) void k_scan3(const int* __restrict__ hist,
                                               const int* __restrict__ boff,
                                               int* __restrict__ iptr,
                                               int* __restrict__ cursor) {
    __shared__ int lds[256];
    int b = blockIdx.x, t = threadIdx.x;
    int idx = b * 256 + t;
    int v = (idx < I_NUMC) ? hist[idx] : 0;
    int x = v;
    #pragma unroll
    for (int o = 1; o < 256; o <<= 1) {
        lds[t] = x; __syncthreads();
        int y = (t >= o) ? lds[t - o] : 0; __syncthreads();
        x += y;
    }
    if (idx < I_NUMC) {
        int excl = boff[b] + x - v;
        iptr[idx] = excl;
        cursor[idx] = excl;
    }
}

// ------- XCD-class-filtered scatter into exact item-CSR positions -------------
// Block class = blockIdx.x & 7 (round-robin block->XCD). Class k handles only
// items with (i>>3)&7 == k, so each 8-item destination window (~2.5 KB) is
// written by a single XCD -> full-line merge in that XCD's L2. Classes stream
// cols1 concurrently (L2/L3-resident). Correct under ANY block->XCD mapping.
__global__ __launch_bounds__(256) void k_scatter(const int* __restrict__ rows1,
                                                 const int* __restrict__ cols1,
                                                 const float* __restrict__ vals1,
                                                 int E1,
                                                 int* __restrict__ cursor,
                                                 int2* __restrict__ item_uv) {
    const int cls  = blockIdx.x & 7;
    const int bsub = blockIdx.x >> 3;
    const int nb   = gridDim.x >> 3;         // blocks per class
    const int E4   = E1 >> 2;
    const int4* c4p = (const int4*)cols1;
    for (int q = bsub * 256 + threadIdx.x; q < E4; q += nb * 256) {
        int4 c4 = c4p[q];
        #pragma unroll
        for (int t = 0; t < 4; ++t) {
            int cv = (t == 0) ? c4.x : (t == 1) ? c4.y : (t == 2) ? c4.z : c4.w;
            int i = cv - U_NUMC;
            if (((i >> 3) & 7) != cls) continue;
            int e = q * 4 + t;
            int pos = atomicAdd(&cursor[i], 1);
            item_uv[pos] = make_int2(rows1[e], __float_as_int(vals1[e]));
        }
    }
    // tail edges (E1 not multiple of 4): handled by bsub==0 block of each class
    if (bsub == 0) {
        int e = E4 * 4 + threadIdx.x;
        if (e < E1) {
            int i = cols1[e] - U_NUMC;
            if (((i >> 3) & 7) == cls) {
                int pos = atomicAdd(&cursor[i], 1);
                item_uv[pos] = make_int2(rows1[e], __float_as_int(vals1[e]));
            }
        }
    }
}

// ---------------- SpMM (CSR-vector): one wave per row, lane = dim -------------
// Edge stream is wave-uniform (readfirstlane'd bounds) -> scalar s_loads, no
// cross-lane shuffles. 8 independent accumulators keep 8 gathers in flight.
// FIRST: gather from split uE/iE (wave-uniform bipartite bases).
template <int FIRST>
__global__ __launch_bounds__(256) void k_spmm(const float* __restrict__ uE,
                                              const float* __restrict__ iE,
                                              const float* __restrict__ f,
                                              float* __restrict__ fn,
                                              const int* __restrict__ uptr,
                                              const int* __restrict__ cols1,
                                              const float* __restrict__ vals1,
                                              const int* __restrict__ iptr,
                                              const int2* __restrict__ item_uv) {
    int wave = (blockIdx.x * blockDim.x + threadIdx.x) >> 6;
    int lane = threadIdx.x & 63;
    if (wave >= NNODES) return;

    const bool isUser = (wave < U_NUMC);
    int beg, end;
    if (isUser) { beg = uptr[wave];           end = uptr[wave + 1]; }
    else        { int i = wave - U_NUMC; beg = iptr[i]; end = iptr[i + 1]; }
    beg = __builtin_amdgcn_readfirstlane(beg);
    end = __builtin_amdgcn_readfirstlane(end);

    const float* fb;
    if (FIRST) fb = isUser ? (iE - (size_t)U_NUMC * EMB) : uE;
    else       fb = f;

    float s0 = 0.f, s1 = 0.f, s2 = 0.f, s3 = 0.f;
    float s4 = 0.f, s5 = 0.f, s6 = 0.f, s7 = 0.f;
    int j = beg;
    if (isUser) {
        for (; j + 8 <= end; j += 8) {
            #pragma unroll
            for (int t = 0; t < 8; ++t) {
                int   c = cols1[j + t];
                float v = vals1[j + t];
                float l = fb[(size_t)c * EMB + lane];
                if (t == 0) s0 += v * l; else if (t == 1) s1 += v * l;
                else if (t == 2) s2 += v * l; else if (t == 3) s3 += v * l;
                else if (t == 4) s4 += v * l; else if (t == 5) s5 += v * l;
                else if (t == 6) s6 += v * l; else s7 += v * l;
            }
        }
        for (; j < end; ++j)
            s0 += vals1[j] * fb[(size_t)cols1[j] * EMB + lane];
    } else {
        for (; j + 8 <= end; j += 8) {
            #pragma unroll
            for (int t = 0; t < 8; ++t) {
                int2 e = item_uv[j + t];
                float v = __int_as_float(e.y);
                float l = fb[(size_t)e.x * EMB + lane];
                if (t == 0) s0 += v * l; else if (t == 1) s1 += v * l;
                else if (t == 2) s2 += v * l; else if (t == 3) s3 += v * l;
                else if (t == 4) s4 += v * l; else if (t == 5) s5 += v * l;
                else if (t == 6) s6 += v * l; else s7 += v * l;
            }
        }
        for (; j < end; ++j) {
            int2 e = item_uv[j];
            s0 += __int_as_float(e.y) * fb[(size_t)e.x * EMB + lane];
        }
    }
    float sum = ((s0 + s1) + (s2 + s3)) + ((s4 + s5) + (s6 + s7));
    fn[(size_t)wave * EMB + lane] = sum;
}

// ------- batched dot: final = (base + g1 + g2 + g3)/4, dot = sum/16 ----------
__global__ __launch_bounds__(256) void k_out(const float* __restrict__ uE,
                                             const float* __restrict__ iE,
                                             const float* __restrict__ g1,
                                             const float* __restrict__ g2,
                                             const float* __restrict__ g3,
                                             const int* __restrict__ userIdx,
                                             const int* __restrict__ itemIdx,
                                             float* __restrict__ out) {
    int wave = (blockIdx.x * blockDim.x + threadIdx.x) >> 6;
    int lane = threadIdx.x & 63;
    if (wave >= NBATCH) return;
    int u  = userIdx[wave];
    int it = itemIdx[wave];
    size_t ou = (size_t)u * EMB + lane;
    size_t oi = (size_t)(U_NUMC + it) * EMB + lane;
    float a = uE[ou] + g1[ou] + g2[ou] + g3[ou];
    float b = iE[(size_t)it * EMB + lane] + g1[oi] + g2[oi] + g3[oi];
    float p = a * b;
    #pragma unroll
    for (int o = 32; o; o >>= 1) p += __shfl_xor(p, o);
    if (lane == 0) out[wave] = p * (1.0f / 16.0f);   // (sum/4)·(sum/4)
}

extern "C" void kernel_launch(void* const* d_in, const int* in_sizes, int n_in,
                              void* d_out, int out_size, void* d_ws, size_t ws_size,
                              hipStream_t stream) {
    const float* uE      = (const float*)d_in[0];
    const float* iE      = (const float*)d_in[1];
    const int*   rows    = (const int*)d_in[2];    // [E], first half sorted by u
    const int*   cols    = (const int*)d_in[3];    // [E], first half = i + U_NUM
    const float* vals    = (const float*)d_in[4];  // [E], symmetric halves
    const int*   userIdx = (const int*)d_in[5];
    const int*   itemIdx = (const int*)d_in[6];
    const int E  = in_sizes[2];
    const int E1 = E / 2;

    char* ws = (char*)d_ws;
    size_t off = 0;
    auto alloc = [&](size_t bytes) -> void* {
        off = (off + 255) & ~(size_t)255;
        void* p = ws + off;
        off += bytes;
        return p;
    };
    float* g1      = (float*)alloc((size_t)NNODES * EMB * 4);
    float* g2      = (float*)alloc((size_t)NNODES * EMB * 4);
    float* g3      = (float*)alloc((size_t)NNODES * EMB * 4);
    int*   uptr    = (int*)alloc((size_t)(U_NUMC + 1) * 4);
    int*   iptr    = (int*)alloc((size_t)(I_NUMC + 1) * 4);
    int*   hist    = (int*)alloc((size_t)I_NUMC * 4);
    int*   cursor  = (int*)alloc((size_t)I_NUMC * 4);
    int*   bsum    = (int*)alloc((size_t)NB_I * 4);
    int*   boff    = (int*)alloc((size_t)NB_I * 4);
    int2*  item_uv = (int2*)alloc((size_t)E1 * 8);

    // zero histogram; build index structures (reused across all 3 layers)
    k_zero<<<(I_NUMC + 255) / 256, 256, 0, stream>>>(hist, I_NUMC);
    k_uptr<<<(U_NUMC + 256) / 256, 256, 0, stream>>>(rows, E1, uptr);
    k_hist<<<(E1 + 255) / 256, 256, 0, stream>>>(cols, E1, hist);
    k_scan1<<<NB_I, 256, 0, stream>>>(hist, bsum);
    k_scan2<<<1, 256, 0, stream>>>(bsum, boff, iptr);
    k_scan3<<<NB_I, 256, 0, stream>>>(hist, boff, iptr, cursor);
    k_scatter<<<2048, 256, 0, stream>>>(rows, cols, vals, E1, cursor, item_uv);

    // 3 propagation layers: g1 = A·feats, g2 = A·g1, g3 = A·g2
    const int spmm_blocks = NNODES / 4;      // 4 waves (rows) per 256-thr block
    k_spmm<1><<<spmm_blocks, 256, 0, stream>>>(uE, iE, nullptr, g1,
                                               uptr, cols, vals, iptr, item_uv);
    k_spmm<0><<<spmm_blocks, 256, 0, stream>>>(uE, iE, g1, g2,
                                               uptr, cols, vals, iptr, item_uv);
    k_spmm<0><<<spmm_blocks, 256, 0, stream>>>(uE, iE, g2, g3,
                                               uptr, cols, vals, iptr, item_uv);

    // final batched dot products
    k_out<<<NBATCH / 4, 256, 0, stream>>>(uE, iE, g1, g2, g3,
                                          userIdx, itemIdx, (float*)d_out);
}